// Round 10
// baseline (35.468 us; speedup 1.0000x reference)
//
#include <hip/hip_runtime.h>
#include <math.h>

typedef _Float16 f16x8 __attribute__((ext_vector_type(8)));
typedef __fp16   fp16v2 __attribute__((ext_vector_type(2)));
typedef float    f32x16 __attribute__((ext_vector_type(16)));

#define THREADS 256
#define YCHUNK  4096  // y points per LDS mega-chunk (32 KB)
#define XPB     128   // x points per block (4 waves * 32 cols)

static __device__ inline unsigned pk2(float a, float b) {
    fp16v2 h = __builtin_amdgcn_cvt_pkrtz(a, b);
    return __builtin_bit_cast(unsigned, h);
}

// Zero the global accumulator {sum (float), counter (int)} each call.
__global__ void init_accum(float* __restrict__ ws) {
    ws[0] = 0.0f;
    ((int*)ws)[1] = 0;
}

// One wave owns 32 x-points (MFMA cols) and scans ALL y (MFMA rows, 32/instr).
// A[y,k] = (y0,y1,y2,|y|^2) f16; B[k,x] = (-2x0,-2x1,-2x2,1) f16 with all
// other K slots zero IN B, so garbage in A's unused K slots contributes 0.
// acc = d^2 - |x|^2; running min on VALU (v_min3), add |x|^2 (f32) at the end.
// Grid pins occupancy at 2 waves/SIMD -> VGPRs up to 256 free; 8 MFMAs in
// flight (named regs, rule #20). Finalize is FUSED: blocks atomicAdd their
// partial into ws[0]; the last block (counter) writes (loss, dist, rate).
__global__ __launch_bounds__(THREADS, 2) void chamfer_kernel(
    const float* __restrict__ pred, const float* __restrict__ targ,
    float* __restrict__ accum, const float* __restrict__ fbpp,
    float* __restrict__ out, int N, int nBlocks)
{
    const int dir = blockIdx.z;
    const float* xsrc = dir == 0 ? pred : targ;
    const float* ysrc = dir == 0 ? targ : pred;
    const int b = blockIdx.y;

    __shared__ uint2 sy[YCHUNK];   // (y0,y1) (y2,|y|^2) packed f16
    __shared__ float swave[4];

    const int tid  = threadIdx.x;
    const int lane = tid & 63;
    const int wave = tid >> 6;
    const int col  = lane & 31;

    // This lane's x column (lanes 32-63 duplicate lanes 0-31).
    const size_t xi = (size_t)(b * N + blockIdx.x * XPB + wave * 32 + col) * 3;
    const float x0 = xsrc[xi], x1 = xsrc[xi + 1], x2 = xsrc[xi + 2];

    const bool act = lane < 32;
    f16x8 bf;
    bf[0] = act ? (_Float16)(-2.0f * x0) : (_Float16)0.0f;
    bf[1] = act ? (_Float16)(-2.0f * x1) : (_Float16)0.0f;
    bf[2] = act ? (_Float16)(-2.0f * x2) : (_Float16)0.0f;
    bf[3] = act ? (_Float16)1.0f : (_Float16)0.0f;
    bf[4] = bf[5] = bf[6] = bf[7] = (_Float16)0.0f;

    f32x16 zacc;
    f32x16 vmin;
#pragma unroll
    for (int r = 0; r < 16; ++r) { zacc[r] = 0.0f; vmin[r] = INFINITY; }

    const float* ybase = ysrc + (size_t)b * N * 3;
    const int nchunks = N / YCHUNK;   // 2

    for (int c = 0; c < nchunks; ++c) {
        __syncthreads();  // previous compute phase done reading sy
        // Stage 4096 y-points: float4-vectorized (12 loads, 4 pts / 3 f4s).
        const float4* yf4 = (const float4*)(ybase + (size_t)c * YCHUNK * 3);
#pragma unroll
        for (int k = 0; k < 4; ++k) {
            const int fbase = k * THREADS * 3 + tid * 3;
            float4 f0 = yf4[fbase + 0];
            float4 f1 = yf4[fbase + 1];
            float4 f2 = yf4[fbase + 2];
            const int yj = (k * THREADS + tid) * 4;
            float n0 = fmaf(f0.x, f0.x, fmaf(f0.y, f0.y, f0.z * f0.z));
            float n1 = fmaf(f0.w, f0.w, fmaf(f1.x, f1.x, f1.y * f1.y));
            float n2 = fmaf(f1.z, f1.z, fmaf(f1.w, f1.w, f2.x * f2.x));
            float n3 = fmaf(f2.y, f2.y, fmaf(f2.z, f2.z, f2.w * f2.w));
            sy[yj + 0] = make_uint2(pk2(f0.x, f0.y), pk2(f0.z, n0));
            sy[yj + 1] = make_uint2(pk2(f0.w, f1.x), pk2(f1.y, n1));
            sy[yj + 2] = make_uint2(pk2(f1.z, f1.w), pk2(f2.x, n2));
            sy[yj + 3] = make_uint2(pk2(f2.y, f2.z), pk2(f2.w, n3));
        }
        __syncthreads();

        // Barrier-free main loop, 8 MFMAs in flight per iteration.
#define LOADJ(j) uint2 lo##j = sy[(i + j) * 32 + col]
#define MFJ(j)                                                            \
        f32x16 ac##j = __builtin_amdgcn_mfma_f32_32x32x16_f16(            \
            __builtin_bit_cast(f16x8,                                     \
                make_uint4(lo##j.x, lo##j.y, 0u, 0u)), bf, zacc, 0, 0, 0)
        for (int i = 0; i < YCHUNK / 32; i += 8) {
            LOADJ(0); LOADJ(1); LOADJ(2); LOADJ(3);
            LOADJ(4); LOADJ(5); LOADJ(6); LOADJ(7);
            MFJ(0); MFJ(1); MFJ(2); MFJ(3);
            MFJ(4); MFJ(5); MFJ(6); MFJ(7);
#pragma unroll
            for (int r = 0; r < 16; ++r) {
                vmin[r] = fminf(fminf(vmin[r], ac0[r]), ac1[r]);  // v_min3
                vmin[r] = fminf(fminf(vmin[r], ac2[r]), ac3[r]);
                vmin[r] = fminf(fminf(vmin[r], ac4[r]), ac5[r]);
                vmin[r] = fminf(fminf(vmin[r], ac6[r]), ac7[r]);
            }
        }
#undef LOADJ
#undef MFJ
    }

    // Reduce 16 regs -> 1, then across the two row-halves (lane ^ 32).
    float v = vmin[0];
#pragma unroll
    for (int r = 1; r < 16; ++r) v = fminf(v, vmin[r]);
    v = fminf(v, __shfl_xor(v, 32));
    float d = v + fmaf(x0, x0, fmaf(x1, x1, x2 * x2));  // + |x|^2 in f32

    // Sum d over the 32 cols of this wave (both halves hold identical values).
#pragma unroll
    for (int off = 16; off > 0; off >>= 1) d += __shfl_xor(d, off);
    if (lane == 0) swave[wave] = d;
    __syncthreads();

    if (tid == 0) {
        float s = swave[0] + swave[1] + swave[2] + swave[3];
        atomicAdd(&accum[0], s);          // device-scope, cross-XCD coherent
        __threadfence();
        int old = atomicAdd((int*)accum + 1, 1);
        if (old == nBlocks - 1) {
            __threadfence();
            float total = atomicAdd(&accum[0], 0.0f);  // atomic read-back
            float dist  = total / (float)(4 * N);
            float rate  = fbpp[0];
            out[0] = dist + rate;
            out[1] = dist;
            out[2] = rate;
        }
    }
}

extern "C" void kernel_launch(void* const* d_in, const int* in_sizes, int n_in,
                              void* d_out, int out_size, void* d_ws, size_t ws_size,
                              hipStream_t stream) {
    const float* pred = (const float*)d_in[0];
    const float* targ = (const float*)d_in[1];
    const float* fbpp = (const float*)d_in[2];
    float* out = (float*)d_out;

    const int B = 4;
    const int N = in_sizes[0] / (B * 3);   // 8192
    float* accum = (float*)d_ws;           // [sum(float), counter(int)]

    init_accum<<<1, 1, 0, stream>>>(accum);

    dim3 grid(N / XPB, B, 2);              // (64, 4, 2) = 512 blocks
    const int nBlocks = grid.x * grid.y * grid.z;
    chamfer_kernel<<<grid, THREADS, 0, stream>>>(pred, targ, accum, fbpp,
                                                 out, N, nBlocks);
}

// Round 11
// 24.524 us; speedup vs baseline: 1.4463x; 1.4463x over previous
//
#include <hip/hip_runtime.h>
#include <math.h>

typedef _Float16 f16x8 __attribute__((ext_vector_type(8)));
typedef __fp16   fp16v2 __attribute__((ext_vector_type(2)));
typedef float    f32x16 __attribute__((ext_vector_type(16)));

#define THREADS 256
#define YCHUNK  4096  // y points per LDS buffer (32 KB each, double-buffered)
#define XPB     128   // x points per block (4 waves * 32 cols)

static __device__ inline unsigned pk2(float a, float b) {
    fp16v2 h = __builtin_amdgcn_cvt_pkrtz(a, b);
    return __builtin_bit_cast(unsigned, h);
}

// Convert 4 y-points (3 float4s) to packed (y0,y1)(y2,|y|^2) f16 LDS entries.
static __device__ inline void packwrite(uint2* dst, float4 f0, float4 f1,
                                        float4 f2) {
    float n0 = fmaf(f0.x, f0.x, fmaf(f0.y, f0.y, f0.z * f0.z));
    float n1 = fmaf(f0.w, f0.w, fmaf(f1.x, f1.x, f1.y * f1.y));
    float n2 = fmaf(f1.z, f1.z, fmaf(f1.w, f1.w, f2.x * f2.x));
    float n3 = fmaf(f2.y, f2.y, fmaf(f2.z, f2.z, f2.w * f2.w));
    dst[0] = make_uint2(pk2(f0.x, f0.y), pk2(f0.z, n0));
    dst[1] = make_uint2(pk2(f0.w, f1.x), pk2(f1.y, n1));
    dst[2] = make_uint2(pk2(f1.z, f1.w), pk2(f2.x, n2));
    dst[3] = make_uint2(pk2(f2.y, f2.z), pk2(f2.w, n3));
}

// One wave owns 32 x-points (MFMA cols) and scans ALL y (MFMA rows, 32/instr).
// A[y,k] = (y0,y1,y2,|y|^2) f16; B[k,x] = (-2x0,-2x1,-2x2,1) f16 with all
// other K slots zero IN B, so garbage in A's unused K slots contributes 0.
// acc = d^2 - |x|^2; running min on VALU (v_min3), |x|^2 added in f32 at end.
// Double-buffered LDS + async-stage split (T14): chunk-1 global loads are
// issued BEFORE chunk-0 compute, so their latency hides under ~5us of MFMA;
// only 2 barriers total. ILP-8 MFMA pipeline (named regs, rule #20).
__global__ __launch_bounds__(THREADS, 2) void chamfer_kernel(
    const float* __restrict__ pred, const float* __restrict__ targ,
    float* __restrict__ partials, int N)
{
    const int dir = blockIdx.z;
    const float* xsrc = dir == 0 ? pred : targ;
    const float* ysrc = dir == 0 ? targ : pred;
    const int b = blockIdx.y;

    __shared__ uint2 sy0[YCHUNK];
    __shared__ uint2 sy1[YCHUNK];
    __shared__ float swave[4];

    const int tid  = threadIdx.x;
    const int lane = tid & 63;
    const int wave = tid >> 6;
    const int col  = lane & 31;

    // This lane's x column (lanes 32-63 duplicate lanes 0-31).
    const size_t xi = (size_t)(b * N + blockIdx.x * XPB + wave * 32 + col) * 3;
    const float x0 = xsrc[xi], x1 = xsrc[xi + 1], x2 = xsrc[xi + 2];

    const bool act = lane < 32;
    f16x8 bf;
    bf[0] = act ? (_Float16)(-2.0f * x0) : (_Float16)0.0f;
    bf[1] = act ? (_Float16)(-2.0f * x1) : (_Float16)0.0f;
    bf[2] = act ? (_Float16)(-2.0f * x2) : (_Float16)0.0f;
    bf[3] = act ? (_Float16)1.0f : (_Float16)0.0f;
    bf[4] = bf[5] = bf[6] = bf[7] = (_Float16)0.0f;

    f32x16 zacc;
    f32x16 vmin;
#pragma unroll
    for (int r = 0; r < 16; ++r) { zacc[r] = 0.0f; vmin[r] = INFINITY; }

    const float4* yf4 = (const float4*)(ysrc + (size_t)b * N * 3);

    // Stage chunk 0 into sy0 (12 float4 loads/thread, 4 pts per 3 f4s).
#pragma unroll
    for (int k = 0; k < 4; ++k) {
        const int fb = k * THREADS * 3 + tid * 3;
        packwrite(&sy0[(k * THREADS + tid) * 4], yf4[fb], yf4[fb + 1],
                  yf4[fb + 2]);
    }

    // Issue chunk-1 global loads NOW; they complete during chunk-0 compute.
#define GDECL(k)                                                           \
    float4 g##k##a = yf4[3072 + k * THREADS * 3 + tid * 3 + 0];            \
    float4 g##k##b = yf4[3072 + k * THREADS * 3 + tid * 3 + 1];            \
    float4 g##k##c = yf4[3072 + k * THREADS * 3 + tid * 3 + 2]
    GDECL(0); GDECL(1); GDECL(2); GDECL(3);
#undef GDECL

    __syncthreads();

    // ---- compute over one LDS buffer: ILP-8 MFMA pipeline ----
#define LOADJ(j, SY) uint2 lo##j = SY[(i + j) * 32 + col]
#define MFJ(j)                                                             \
    f32x16 ac##j = __builtin_amdgcn_mfma_f32_32x32x16_f16(                 \
        __builtin_bit_cast(f16x8,                                          \
            make_uint4(lo##j.x, lo##j.y, 0u, 0u)), bf, zacc, 0, 0, 0)
#define COMPUTE(SY)                                                        \
    for (int i = 0; i < YCHUNK / 32; i += 8) {                             \
        LOADJ(0, SY); LOADJ(1, SY); LOADJ(2, SY); LOADJ(3, SY);            \
        LOADJ(4, SY); LOADJ(5, SY); LOADJ(6, SY); LOADJ(7, SY);            \
        MFJ(0); MFJ(1); MFJ(2); MFJ(3);                                    \
        MFJ(4); MFJ(5); MFJ(6); MFJ(7);                                    \
        _Pragma("unroll")                                                  \
        for (int r = 0; r < 16; ++r) {                                     \
            vmin[r] = fminf(fminf(vmin[r], ac0[r]), ac1[r]);               \
            vmin[r] = fminf(fminf(vmin[r], ac2[r]), ac3[r]);               \
            vmin[r] = fminf(fminf(vmin[r], ac4[r]), ac5[r]);               \
            vmin[r] = fminf(fminf(vmin[r], ac6[r]), ac7[r]);               \
        }                                                                  \
    }

    COMPUTE(sy0)

    // Stage chunk 1 from the already-arrived registers, one barrier, compute.
    packwrite(&sy1[(0 * THREADS + tid) * 4], g0a, g0b, g0c);
    packwrite(&sy1[(1 * THREADS + tid) * 4], g1a, g1b, g1c);
    packwrite(&sy1[(2 * THREADS + tid) * 4], g2a, g2b, g2c);
    packwrite(&sy1[(3 * THREADS + tid) * 4], g3a, g3b, g3c);
    __syncthreads();

    COMPUTE(sy1)
#undef COMPUTE
#undef LOADJ
#undef MFJ

    // Reduce 16 regs -> 1, then across the two row-halves (lane ^ 32).
    float v = vmin[0];
#pragma unroll
    for (int r = 1; r < 16; ++r) v = fminf(v, vmin[r]);
    v = fminf(v, __shfl_xor(v, 32));
    float d = v + fmaf(x0, x0, fmaf(x1, x1, x2 * x2));  // + |x|^2 in f32

    // Sum d over the 32 cols of this wave (both halves hold identical values).
#pragma unroll
    for (int off = 16; off > 0; off >>= 1) d += __shfl_xor(d, off);
    if (lane == 0) swave[wave] = d;
    __syncthreads();
    if (tid == 0) {
        float s = swave[0] + swave[1] + swave[2] + swave[3];
        int bid = blockIdx.x + gridDim.x * (blockIdx.y + gridDim.y * blockIdx.z);
        partials[bid] = s;
    }
}

// Sum all 512 block partials; dist = sum / (B*N); out = (loss, dist, rate).
__global__ __launch_bounds__(512) void finalize(
    const float* __restrict__ partials, const float* __restrict__ fbpp,
    float* __restrict__ out, int nPartials, int totalPts)
{
    __shared__ float sw[8];
    const int tid = threadIdx.x;
    float v = (tid < nPartials) ? partials[tid] : 0.0f;
#pragma unroll
    for (int off = 32; off > 0; off >>= 1) v += __shfl_xor(v, off);
    if ((tid & 63) == 0) sw[tid >> 6] = v;
    __syncthreads();
    if (tid == 0) {
        float t = 0.0f;
#pragma unroll
        for (int w = 0; w < 8; ++w) t += sw[w];
        float dist = t / (float)totalPts;
        float rate = fbpp[0];
        out[0] = dist + rate;
        out[1] = dist;
        out[2] = rate;
    }
}

extern "C" void kernel_launch(void* const* d_in, const int* in_sizes, int n_in,
                              void* d_out, int out_size, void* d_ws, size_t ws_size,
                              hipStream_t stream) {
    const float* pred = (const float*)d_in[0];
    const float* targ = (const float*)d_in[1];
    const float* fbpp = (const float*)d_in[2];
    float* out = (float*)d_out;

    const int B = 4;
    const int N = in_sizes[0] / (B * 3);   // 8192
    float* partials = (float*)d_ws;        // 2 * B * (N/XPB) floats = 512

    dim3 grid(N / XPB, B, 2);              // (64, 4, 2) = 512 blocks
    chamfer_kernel<<<grid, THREADS, 0, stream>>>(pred, targ, partials, N);

    const int nPartials = (N / XPB) * B * 2;  // 512
    finalize<<<1, 512, 0, stream>>>(partials, fbpp, out, nPartials, B * N);
}